// Round 2
// baseline (224.188 us; speedup 1.0000x reference)
//
#include <hip/hip_runtime.h>
#include <hip/hip_bf16.h>

// B=2, C=8, L=1024, H=512
// out[((b*1024+l)*1024+m)*8 + c] = a[b,c,l] + bb[b,c,m] + sum_h start*v4*end
//
// Kernel 1: per-row dots a = start.(v1+v3), bb = end.(v2-v3) -> ws (32768 floats)
// Kernel 2: bf16 MFMA batched GEMM, WG tile 128x128 x 2 c-planes, epilogue adds a+bb.
//   Round 2 change (ONLY): software pipeline — register prefetch of next K-step +
//   LDS double-buffer, ONE barrier per K-step. Pad-40 layout and all indexing
//   identical to the verified round-0 kernel.

typedef short bf16x8 __attribute__((ext_vector_type(8)));
typedef float f32x4 __attribute__((ext_vector_type(4)));

__device__ __forceinline__ unsigned short f2bf(float x) {
    unsigned int u = __float_as_uint(x);
    u += 0x7fffu + ((u >> 16) & 1u);   // round-to-nearest-even
    return (unsigned short)(u >> 16);
}

__device__ __forceinline__ uint4 pack8(float4 a, float4 b) {
    uint4 r;
    r.x = (unsigned)f2bf(a.x) | ((unsigned)f2bf(a.y) << 16);
    r.y = (unsigned)f2bf(a.z) | ((unsigned)f2bf(a.w) << 16);
    r.z = (unsigned)f2bf(b.x) | ((unsigned)f2bf(b.y) << 16);
    r.w = (unsigned)f2bf(b.z) | ((unsigned)f2bf(b.w) << 16);
    return r;
}

// ---------------- Kernel 1: row sums (verified, unchanged) ----------------
__global__ __launch_bounds__(256) void sums_k(const float* __restrict__ sh,
                                              const float* __restrict__ eh,
                                              const float* __restrict__ v,
                                              float* __restrict__ ws) {
    const int gid  = blockIdx.x * 256 + threadIdx.x;
    const int row  = gid >> 6;
    const int lane = gid & 63;
    const int h    = lane * 8;

    const float* ps = sh + (size_t)row * 512 + h;
    const float* pe = eh + (size_t)row * 512 + h;
    float4 s0 = *(const float4*)ps;       float4 s1 = *(const float4*)(ps + 4);
    float4 e0 = *(const float4*)pe;       float4 e1 = *(const float4*)(pe + 4);
    float4 v10 = *(const float4*)(v + h);        float4 v11 = *(const float4*)(v + h + 4);
    float4 v20 = *(const float4*)(v + 512 + h);  float4 v21 = *(const float4*)(v + 512 + h + 4);
    float4 v30 = *(const float4*)(v + 1024 + h); float4 v31 = *(const float4*)(v + 1024 + h + 4);

    float da = s0.x*(v10.x+v30.x) + s0.y*(v10.y+v30.y) + s0.z*(v10.z+v30.z) + s0.w*(v10.w+v30.w)
             + s1.x*(v11.x+v31.x) + s1.y*(v11.y+v31.y) + s1.z*(v11.z+v31.z) + s1.w*(v11.w+v31.w);
    float db = e0.x*(v20.x-v30.x) + e0.y*(v20.y-v30.y) + e0.z*(v20.z-v30.z) + e0.w*(v20.w-v30.w)
             + e1.x*(v21.x-v31.x) + e1.y*(v21.y-v31.y) + e1.z*(v21.z-v31.z) + e1.w*(v21.w-v31.w);

    #pragma unroll
    for (int off = 32; off >= 1; off >>= 1) {
        da += __shfl_down(da, off, 64);
        db += __shfl_down(db, off, 64);
    }
    if (lane == 0) {
        ws[row]         = da;
        ws[16384 + row] = db;
    }
}

// ---------------- Kernel 2: fused batched GEMM, pipelined ----------------
// grid = 512: bid = cp*128 + (b*64 + lt*8 + mt); cp = c-pair (0..3)
__global__ __launch_bounds__(256, 2) void gemm_k(const float* __restrict__ sh,
                                                 const float* __restrict__ eh,
                                                 const float* __restrict__ v,
                                                 const float* __restrict__ ws,
                                                 float* __restrict__ out) {
    // double-buffered LDS: [p][c2][row 0..127][k 0..31 (+8 pad)] bf16  (80 KB total)
    __shared__ __align__(16) unsigned short As[2][2 * 128 * 40];
    __shared__ __align__(16) unsigned short Bs[2][2 * 128 * 40];

    const int t    = threadIdx.x;
    const int bid  = blockIdx.x;
    const int cp   = bid >> 7;
    const int rem  = bid & 127;
    const int b    = rem >> 6;
    const int lt   = (rem >> 3) & 7;
    const int mt   = rem & 7;
    const int lbase = lt * 128, mbase = mt * 128;

    const int lane = t & 63, wave = t >> 6;
    const int ln15 = lane & 15, quad = lane >> 4;
    const int wl   = wave >> 1, wm = wave & 1;

    const int k8   = t & 3;       // fixed k-subblock per thread
    const int lrow = t >> 2;      // 0..63

    const int c0 = b * 8 + cp * 2;
    const float* baseA = sh + (size_t)c0 * 1024 * 512;
    const float* baseB = eh + (size_t)c0 * 1024 * 512;

    // per-thread row pointers and LDS write indices (pad-40, same as round 0)
    const float* pA[4];
    const float* pB[4];
    int wIdx[4];
    #pragma unroll
    for (int s = 0; s < 4; ++s) {
        const int c2 = s >> 1, row = (s & 1) * 64 + lrow;
        pA[s] = baseA + ((size_t)c2 * 1024 + lbase + row) * 512 + k8 * 8;
        pB[s] = baseB + ((size_t)c2 * 1024 + mbase + row) * 512 + k8 * 8;
        wIdx[s] = (c2 * 128 + row) * 40 + k8 * 8;
    }

    // prologue loads for K-step 0
    float4 xaA[4][2], xbA[4][2], xaB[4][2], xbB[4][2];
    #pragma unroll
    for (int s = 0; s < 4; ++s) {
        xaA[s][0] = *(const float4*)pA[s];  xaA[s][1] = *(const float4*)(pA[s] + 4);
        xbA[s][0] = *(const float4*)pB[s];  xbA[s][1] = *(const float4*)(pB[s] + 4);
    }

    f32x4 acc[2][4][4] = {};

    // pack raw fp32 regs -> bf16 LDS buffer p; v4 applied to A side (as round 0)
    auto pack_to = [&](int p, float4 (&ca)[4][2], float4 (&cb)[4][2], int k0) {
        float4 w0 = *(const float4*)(v + 1536 + k0);
        float4 w1 = *(const float4*)(v + 1536 + k0 + 4);
        #pragma unroll
        for (int s = 0; s < 4; ++s) {
            float4 a0 = ca[s][0], a1 = ca[s][1];
            a0.x *= w0.x; a0.y *= w0.y; a0.z *= w0.z; a0.w *= w0.w;
            a1.x *= w1.x; a1.y *= w1.y; a1.z *= w1.z; a1.w *= w1.w;
            *(uint4*)&As[p][wIdx[s]] = pack8(a0, a1);
            *(uint4*)&Bs[p][wIdx[s]] = pack8(cb[s][0], cb[s][1]);
        }
    };

    auto load_next = [&](float4 (&na)[4][2], float4 (&nb)[4][2], int koff) {
        #pragma unroll
        for (int s = 0; s < 4; ++s) {
            const float* a  = pA[s] + koff;
            const float* bp = pB[s] + koff;
            na[s][0] = *(const float4*)a;   na[s][1] = *(const float4*)(a + 4);
            nb[s][0] = *(const float4*)bp;  nb[s][1] = *(const float4*)(bp + 4);
        }
    };

    auto mfma_ph = [&](int p) {
        #pragma unroll
        for (int c2 = 0; c2 < 2; ++c2) {
            bf16x8 aF[4], bF[4];
            #pragma unroll
            for (int i = 0; i < 4; ++i) {
                aF[i] = *(const bf16x8*)&As[p][(c2 * 128 + wl * 64 + i * 16 + ln15) * 40 + quad * 8];
                bF[i] = *(const bf16x8*)&Bs[p][(c2 * 128 + wm * 64 + i * 16 + ln15) * 40 + quad * 8];
            }
            #pragma unroll
            for (int i = 0; i < 4; ++i)
                #pragma unroll
                for (int j = 0; j < 4; ++j)
                    acc[c2][i][j] = __builtin_amdgcn_mfma_f32_16x16x32_bf16(
                        aF[i], bF[j], acc[c2][i][j], 0, 0, 0);
        }
    };

    // main loop: 16 K-steps, 2 per iteration, ONE barrier per K-step.
    // Buffer p written at step n (before sync n); read after sync n; next write of
    // p is after sync n+1, which orders against all step-n reads. Race-free.
    int kb = k8 * 8;
    for (int it = 0; it < 7; ++it) {
        pack_to(0, xaA, xbA, kb);
        load_next(xaB, xbB, 32);          // in flight across sync + mfma_ph(0)
        __syncthreads();
        mfma_ph(0);

        pack_to(1, xaB, xbB, kb + 32);
        load_next(xaA, xbA, 64);          // in flight across sync + mfma_ph(1)
        __syncthreads();
        mfma_ph(1);

        #pragma unroll
        for (int s = 0; s < 4; ++s) { pA[s] += 64; pB[s] += 64; }
        kb += 64;
    }
    // peeled last two K-steps (no prefetch past the array end)
    pack_to(0, xaA, xbA, kb);
    load_next(xaB, xbB, 32);
    __syncthreads();
    mfma_ph(0);

    pack_to(1, xaB, xbB, kb + 32);
    __syncthreads();
    mfma_ph(1);

    // epilogue: add a[l] + bb[m], write float2 (both c's of the pair) — verified round-0 code
    const float* aw = ws;
    const float* bw = ws + 16384;
    #pragma unroll
    for (int i = 0; i < 4; ++i)
        #pragma unroll
        for (int r = 0; r < 4; ++r) {
            const int l = lbase + wl * 64 + i * 16 + quad * 4 + r;
            const float av0 = aw[c0 * 1024 + l];
            const float av1 = aw[(c0 + 1) * 1024 + l];
            #pragma unroll
            for (int j = 0; j < 4; ++j) {
                const int m = mbase + wm * 64 + j * 16 + ln15;
                const float bv0 = bw[c0 * 1024 + m];
                const float bv1 = bw[(c0 + 1) * 1024 + m];
                float2 o;
                o.x = acc[0][i][j][r] + av0 + bv0;
                o.y = acc[1][i][j][r] + av1 + bv1;
                *(float2*)&out[(size_t)((b * 1024 + l) * 1024 + m) * 8 + cp * 2] = o;
            }
        }
}

extern "C" void kernel_launch(void* const* d_in, const int* in_sizes, int n_in,
                              void* d_out, int out_size, void* d_ws, size_t ws_size,
                              hipStream_t stream) {
    (void)in_sizes; (void)n_in; (void)out_size; (void)ws_size;
    const float* sh = (const float*)d_in[0];
    const float* eh = (const float*)d_in[1];
    const float* v  = (const float*)d_in[2];
    float* out = (float*)d_out;
    float* ws  = (float*)d_ws;   // needs 32768 floats = 128 KB

    sums_k<<<4096, 256, 0, stream>>>(sh, eh, v, ws);
    gemm_k<<<512, 256, 0, stream>>>(sh, eh, v, ws, out);
}

// Round 3
// 209.570 us; speedup vs baseline: 1.0697x; 1.0697x over previous
//
#include <hip/hip_runtime.h>
#include <hip/hip_bf16.h>

// B=2, C=8, L=1024, H=512
// out[((b*1024+l)*1024+m)*8 + c] = a[b,c,l] + bb[b,c,m] + sum_h start*v4*end
//
// Single kernel (round 3): verified round-0 GEMM structure (single-buffer LDS,
// pad-40, two barriers per K-step) + in-loop fusion of the row dots:
//   a  = start.(v1+v3), bb = end.(v2-v3)
// accumulated from the raw fp32 staging registers (each thread's k8-slice
// partitions K exactly across the 16 K-steps), reduced via 2-step shfl_xor
// butterfly over the k8 quad, staged in LDS for the epilogue.
// sums_k kernel and workspace eliminated.

typedef short bf16x8 __attribute__((ext_vector_type(8)));
typedef float f32x4 __attribute__((ext_vector_type(4)));

__device__ __forceinline__ unsigned short f2bf(float x) {
    unsigned int u = __float_as_uint(x);
    u += 0x7fffu + ((u >> 16) & 1u);   // round-to-nearest-even
    return (unsigned short)(u >> 16);
}

__device__ __forceinline__ uint4 pack8(float4 a, float4 b) {
    uint4 r;
    r.x = (unsigned)f2bf(a.x) | ((unsigned)f2bf(a.y) << 16);
    r.y = (unsigned)f2bf(a.z) | ((unsigned)f2bf(a.w) << 16);
    r.z = (unsigned)f2bf(b.x) | ((unsigned)f2bf(b.y) << 16);
    r.w = (unsigned)f2bf(b.z) | ((unsigned)f2bf(b.w) << 16);
    return r;
}

// grid = 512: bid = cp*128 + (b*64 + lt*8 + mt); cp = c-pair (0..3)
// same-tile c-pairs differ by 128 in bid -> same XCD (bid%8 equal) for L2 write-combining.
__global__ __launch_bounds__(256, 2) void gemm_k(const float* __restrict__ sh,
                                                 const float* __restrict__ eh,
                                                 const float* __restrict__ v,
                                                 float* __restrict__ out) {
    // LDS: [c2][row 0..127][k 0..31 (+8 pad)] bf16  (40 KB, round-0 layout)
    __shared__ __align__(16) unsigned short As[2 * 128 * 40];
    __shared__ __align__(16) unsigned short Bs[2 * 128 * 40];
    __shared__ __align__(16) float v13_s[512], v23_s[512], v4_s[512];  // 6 KB
    __shared__ float a_s[2][128], b_s[2][128];                          // 2 KB

    const int t    = threadIdx.x;
    const int bid  = blockIdx.x;
    const int cp   = bid >> 7;
    const int rem  = bid & 127;
    const int b    = rem >> 6;
    const int lt   = (rem >> 3) & 7;
    const int mt   = rem & 7;
    const int lbase = lt * 128, mbase = mt * 128;

    const int lane = t & 63, wave = t >> 6;
    const int ln15 = lane & 15, quad = lane >> 4;
    const int wl   = wave >> 1, wm = wave & 1;

    const int k8   = t & 3;       // fixed k-subblock per thread
    const int lrow = t >> 2;      // 0..63

    const int c0 = b * 8 + cp * 2;
    const float* baseA = sh + (size_t)c0 * 1024 * 512;
    const float* baseB = eh + (size_t)c0 * 1024 * 512;

    // stage combined v-weights in LDS; first in-loop barrier orders this
    {
        const int i2 = t * 2;
        float2 x1 = *(const float2*)&v[i2];
        float2 x2 = *(const float2*)&v[512 + i2];
        float2 x3 = *(const float2*)&v[1024 + i2];
        float2 x4 = *(const float2*)&v[1536 + i2];
        v13_s[i2] = x1.x + x3.x;  v13_s[i2 + 1] = x1.y + x3.y;
        v23_s[i2] = x2.x - x3.x;  v23_s[i2 + 1] = x2.y - x3.y;
        v4_s[i2]  = x4.x;         v4_s[i2 + 1]  = x4.y;
    }

    f32x4 acc[2][4][4] = {};
    float da[4] = {0.f, 0.f, 0.f, 0.f};
    float db[4] = {0.f, 0.f, 0.f, 0.f};

    for (int ks = 0; ks < 16; ++ks) {
        const int k0 = ks * 32 + k8 * 8;

        float4 xa[4][2], xb[4][2];
        #pragma unroll
        for (int s = 0; s < 4; ++s) {
            const int c2  = s >> 1;
            const int row = (s & 1) * 64 + lrow;
            const float* pa = baseA + ((size_t)c2 * 1024 + lbase + row) * 512 + k0;
            const float* pb = baseB + ((size_t)c2 * 1024 + mbase + row) * 512 + k0;
            xa[s][0] = *(const float4*)pa;       xa[s][1] = *(const float4*)(pa + 4);
            xb[s][0] = *(const float4*)pb;       xb[s][1] = *(const float4*)(pb + 4);
        }

        __syncthreads();   // previous iter's LDS reads done (and v-staging, iter 0)

        float4 w13a = *(const float4*)&v13_s[k0];
        float4 w13b = *(const float4*)&v13_s[k0 + 4];
        float4 w23a = *(const float4*)&v23_s[k0];
        float4 w23b = *(const float4*)&v23_s[k0 + 4];
        float4 w4a  = *(const float4*)&v4_s[k0];
        float4 w4b  = *(const float4*)&v4_s[k0 + 4];

        #pragma unroll
        for (int s = 0; s < 4; ++s) {
            const int c2  = s >> 1;
            const int row = (s & 1) * 64 + lrow;
            float4 a0 = xa[s][0], a1 = xa[s][1];
            float4 b0 = xb[s][0], b1 = xb[s][1];
            // fused row-dot partials on raw fp32 values
            da[s] += a0.x * w13a.x + a0.y * w13a.y + a0.z * w13a.z + a0.w * w13a.w
                   + a1.x * w13b.x + a1.y * w13b.y + a1.z * w13b.z + a1.w * w13b.w;
            db[s] += b0.x * w23a.x + b0.y * w23a.y + b0.z * w23a.z + b0.w * w23a.w
                   + b1.x * w23b.x + b1.y * w23b.y + b1.z * w23b.z + b1.w * w23b.w;
            // v4 folded into A side (as round 0)
            a0.x *= w4a.x; a0.y *= w4a.y; a0.z *= w4a.z; a0.w *= w4a.w;
            a1.x *= w4b.x; a1.y *= w4b.y; a1.z *= w4b.z; a1.w *= w4b.w;
            *(uint4*)&As[(c2 * 128 + row) * 40 + k8 * 8] = pack8(a0, a1);
            *(uint4*)&Bs[(c2 * 128 + row) * 40 + k8 * 8] = pack8(b0, b1);
        }
        __syncthreads();

        bf16x8 aF[2][4], bF[2][4];
        #pragma unroll
        for (int c2 = 0; c2 < 2; ++c2)
            #pragma unroll
            for (int i = 0; i < 4; ++i) {
                aF[c2][i] = *(const bf16x8*)&As[(c2 * 128 + wl * 64 + i * 16 + ln15) * 40 + quad * 8];
                bF[c2][i] = *(const bf16x8*)&Bs[(c2 * 128 + wm * 64 + i * 16 + ln15) * 40 + quad * 8];
            }
        #pragma unroll
        for (int c2 = 0; c2 < 2; ++c2)
            #pragma unroll
            for (int i = 0; i < 4; ++i)
                #pragma unroll
                for (int j = 0; j < 4; ++j)
                    acc[c2][i][j] = __builtin_amdgcn_mfma_f32_16x16x32_bf16(
                        aF[c2][i], bF[c2][j], acc[c2][i][j], 0, 0, 0);
    }

    // reduce dot partials over the k8 quad (threads of one lrow are 4 consecutive
    // lanes of the same wave: lane = (lrow&15)*4 + k8)
    #pragma unroll
    for (int s = 0; s < 4; ++s) {
        da[s] += __shfl_xor(da[s], 1, 64);
        da[s] += __shfl_xor(da[s], 2, 64);
        db[s] += __shfl_xor(db[s], 1, 64);
        db[s] += __shfl_xor(db[s], 2, 64);
    }
    if (k8 == 0) {
        #pragma unroll
        for (int s = 0; s < 4; ++s) {
            const int c2 = s >> 1, row = (s & 1) * 64 + lrow;
            a_s[c2][row] = da[s];
            b_s[c2][row] = db[s];
        }
    }
    __syncthreads();

    // epilogue: add a[l] + bb[m] from LDS, write float2 (both c's of the pair)
    #pragma unroll
    for (int i = 0; i < 4; ++i)
        #pragma unroll
        for (int r = 0; r < 4; ++r) {
            const int ll = wl * 64 + i * 16 + quad * 4 + r;
            const int l  = lbase + ll;
            const float av0 = a_s[0][ll];
            const float av1 = a_s[1][ll];
            #pragma unroll
            for (int j = 0; j < 4; ++j) {
                const int mm = wm * 64 + j * 16 + ln15;
                const int m  = mbase + mm;
                const float bv0 = b_s[0][mm];
                const float bv1 = b_s[1][mm];
                float2 o;
                o.x = acc[0][i][j][r] + av0 + bv0;
                o.y = acc[1][i][j][r] + av1 + bv1;
                *(float2*)&out[(size_t)((b * 1024 + l) * 1024 + m) * 8 + cp * 2] = o;
            }
        }
}

extern "C" void kernel_launch(void* const* d_in, const int* in_sizes, int n_in,
                              void* d_out, int out_size, void* d_ws, size_t ws_size,
                              hipStream_t stream) {
    (void)in_sizes; (void)n_in; (void)out_size; (void)d_ws; (void)ws_size;
    const float* sh = (const float*)d_in[0];
    const float* eh = (const float*)d_in[1];
    const float* v  = (const float*)d_in[2];
    gemm_k<<<512, 256, 0, stream>>>(sh, eh, v, (float*)d_out);
}